// Round 1
// baseline (40.316 us; speedup 1.0000x reference)
//
#include <hip/hip_runtime.h>
#include <math.h>

#define HH   512
#define WW   512
#define KG   256
#define NPIX (HH * WW)
#define EPSF 1e-6f

// One kernel: each block recomputes the per-gaussian parameter table into LDS
// (cost: 256 threads x a few transcendentals, once per block), then each
// thread renders 2 pixels, looping over all 256 gaussians.
__global__ __launch_bounds__(256, 2) void gauss_render(
    const float* __restrict__ grid,          // (H,W,2)
    const float* __restrict__ mu,            // (K,2)
    const float* __restrict__ log_scales,    // (K,2)
    const float* __restrict__ theta,         // (K,)
    const float* __restrict__ color_logits,  // (K,3)
    const float* __restrict__ log_amp,       // (K,1)
    float* __restrict__ out)                 // (H,W,3)
{
    __shared__ float4 sp[3 * KG];   // 12 KB: {mux,muy,c,s} {isx,isy,ln(amp),col0} {col1,col2,-,-}

    const int tid = threadIdx.x;
    {
        const int k = tid;                       // blockDim.x == KG == 256
        float mux = mu[2 * k + 0];
        float muy = mu[2 * k + 1];
        float sx  = expf(log_scales[2 * k + 0]);
        float sy  = expf(log_scales[2 * k + 1]);
        float isx = 1.0f / (sx * sx + EPSF);
        float isy = 1.0f / (sy * sy + EPSF);
        float t   = theta[k];
        float c   = cosf(t);
        float s   = sinf(t);
        float la  = log_amp[k];
        float amp = (la > 20.0f) ? la : log1pf(expf(la));  // softplus
        float lnA = logf(amp);
        float c0  = 1.0f / (1.0f + expf(-color_logits[3 * k + 0]));
        float c1  = 1.0f / (1.0f + expf(-color_logits[3 * k + 1]));
        float c2  = 1.0f / (1.0f + expf(-color_logits[3 * k + 2]));
        sp[3 * k + 0] = make_float4(mux, muy, c, s);
        sp[3 * k + 1] = make_float4(isx, isy, lnA, c0);
        sp[3 * k + 2] = make_float4(c1, c2, 0.0f, 0.0f);
    }
    __syncthreads();

    const int g    = blockIdx.x * 256 + tid;   // 0 .. NPIX/2 - 1
    const int pix0 = g;
    const int pix1 = g + NPIX / 2;

    const float2 p0 = reinterpret_cast<const float2*>(grid)[pix0];
    const float2 p1 = reinterpret_cast<const float2*>(grid)[pix1];

    float den0 = 0.f, r0 = 0.f, gg0 = 0.f, b0 = 0.f;
    float den1 = 0.f, r1 = 0.f, gg1 = 0.f, b1 = 0.f;

    #pragma unroll 4
    for (int k = 0; k < KG; ++k) {
        const float4 a = sp[3 * k + 0];
        const float4 b = sp[3 * k + 1];
        const float4 c = sp[3 * k + 2];
        // pixel 0
        {
            float dx = p0.x - a.x, dy = p0.y - a.y;
            float vx = fmaf(dx, a.z, dy * a.w);     //  dx*c + dy*s
            float vy = fmaf(dy, a.z, -dx * a.w);    // -dx*s + dy*c
            float q  = fmaf(vx * vx, b.x, vy * vy * b.y);
            float w  = __expf(fmaf(q, -0.5f, b.z)); // exp(-q/2) * amp
            den0 += w;
            r0  = fmaf(w, b.w, r0);
            gg0 = fmaf(w, c.x, gg0);
            b0  = fmaf(w, c.y, b0);
        }
        // pixel 1
        {
            float dx = p1.x - a.x, dy = p1.y - a.y;
            float vx = fmaf(dx, a.z, dy * a.w);
            float vy = fmaf(dy, a.z, -dx * a.w);
            float q  = fmaf(vx * vx, b.x, vy * vy * b.y);
            float w  = __expf(fmaf(q, -0.5f, b.z));
            den1 += w;
            r1  = fmaf(w, b.w, r1);
            gg1 = fmaf(w, c.x, gg1);
            b1  = fmaf(w, c.y, b1);
        }
    }

    const float inv0 = 1.0f / (den0 + EPSF);
    const float inv1 = 1.0f / (den1 + EPSF);

    out[3 * pix0 + 0] = fminf(fmaxf(r0  * inv0, 0.f), 1.f);
    out[3 * pix0 + 1] = fminf(fmaxf(gg0 * inv0, 0.f), 1.f);
    out[3 * pix0 + 2] = fminf(fmaxf(b0  * inv0, 0.f), 1.f);
    out[3 * pix1 + 0] = fminf(fmaxf(r1  * inv1, 0.f), 1.f);
    out[3 * pix1 + 1] = fminf(fmaxf(gg1 * inv1, 0.f), 1.f);
    out[3 * pix1 + 2] = fminf(fmaxf(b1  * inv1, 0.f), 1.f);
}

extern "C" void kernel_launch(void* const* d_in, const int* in_sizes, int n_in,
                              void* d_out, int out_size, void* d_ws, size_t ws_size,
                              hipStream_t stream) {
    const float* grid         = (const float*)d_in[0];
    const float* mu           = (const float*)d_in[1];
    const float* log_scales   = (const float*)d_in[2];
    const float* theta        = (const float*)d_in[3];
    const float* color_logits = (const float*)d_in[4];
    const float* log_amp      = (const float*)d_in[5];
    float* out = (float*)d_out;

    const int threads = 256;
    const int blocks  = (NPIX / 2) / threads;  // 512 blocks, 2 px/thread
    hipLaunchKernelGGL(gauss_render, dim3(blocks), dim3(threads), 0, stream,
                       grid, mu, log_scales, theta, color_logits, log_amp, out);
}

// Round 2
// 37.016 us; speedup vs baseline: 1.0891x; 1.0891x over previous
//
#include <hip/hip_runtime.h>
#include <math.h>

#define HH   512
#define WW   512
#define KG   256
#define NPIX (HH * WW)
#define EPSF 1e-6f

// ---------------------------------------------------------------------------
// Pass 1: fold each gaussian into 12 floats (3x float4) in d_ws:
//   q0 = {ca, cb, cc, cd}   e = ca*x^2 + cb*y^2 + cc*x*y + cd*x + ce*y + cf
//   q1 = {ce, cf, col0, col1}
//   q2 = {col2, 0, 0, 0}
// where w = exp(e) already includes the amplitude (lnA folded into cf).
// ---------------------------------------------------------------------------
__global__ __launch_bounds__(KG) void gauss_precompute(
    const float* __restrict__ mu,            // (K,2)
    const float* __restrict__ log_scales,    // (K,2)
    const float* __restrict__ theta,         // (K,)
    const float* __restrict__ color_logits,  // (K,3)
    const float* __restrict__ log_amp,       // (K,1)
    float4* __restrict__ params)             // (K,3)
{
    const int k = threadIdx.x;
    const float mx  = mu[2 * k + 0];
    const float my  = mu[2 * k + 1];
    const float sx  = expf(log_scales[2 * k + 0]);
    const float sy  = expf(log_scales[2 * k + 1]);
    const float isx = 1.0f / (sx * sx + EPSF);
    const float isy = 1.0f / (sy * sy + EPSF);
    const float t   = theta[k];
    const float c   = cosf(t);
    const float s   = sinf(t);

    // q = A dx^2 + B dy^2 + C dx dy  (dx = x-mx, dy = y-my)
    const float A = c * c * isx + s * s * isy;
    const float B = s * s * isx + c * c * isy;
    const float C = 2.0f * c * s * (isx - isy);

    const float la  = log_amp[k];
    const float amp = (la > 20.0f) ? la : log1pf(expf(la));  // softplus
    const float lnA = logf(amp);

    // e = lnA - 0.5 q, expanded in x,y:
    const float ca = -0.5f * A;
    const float cb = -0.5f * B;
    const float cc = -0.5f * C;
    const float cd = A * mx + 0.5f * C * my;
    const float ce = B * my + 0.5f * C * mx;
    const float cf = lnA - 0.5f * (A * mx * mx + B * my * my + C * mx * my);

    const float c0 = 1.0f / (1.0f + expf(-color_logits[3 * k + 0]));
    const float c1 = 1.0f / (1.0f + expf(-color_logits[3 * k + 1]));
    const float c2 = 1.0f / (1.0f + expf(-color_logits[3 * k + 2]));

    params[3 * k + 0] = make_float4(ca, cb, cc, cd);
    params[3 * k + 1] = make_float4(ce, cf, c0, c1);
    params[3 * k + 2] = make_float4(c2, 0.0f, 0.0f, 0.0f);
}

// ---------------------------------------------------------------------------
// Pass 2: render. 2 pixels/thread as float2 "lanes" (pairwise math invites
// v_pk_fma_f32). Gaussian params read with a wave-uniform index -> scalar
// (s_load) path, no LDS, no vector-mem in the loop.
// ---------------------------------------------------------------------------
__device__ __forceinline__ float2 pk_fma_s(float s, float2 b, float2 c) {
    return make_float2(fmaf(s, b.x, c.x), fmaf(s, b.y, c.y));
}

__global__ __launch_bounds__(256, 2) void gauss_render(
    const float* __restrict__ grid,          // (H,W,2)
    const float4* __restrict__ params,       // (K,3)
    float* __restrict__ out)                 // (H,W,3)
{
    const int g    = blockIdx.x * 256 + threadIdx.x;   // 0 .. NPIX/2-1
    const int pix0 = g;
    const int pix1 = g + NPIX / 2;

    const float2 p0 = reinterpret_cast<const float2*>(grid)[pix0];
    const float2 p1 = reinterpret_cast<const float2*>(grid)[pix1];

    const float2 X  = make_float2(p0.x, p1.x);
    const float2 Y  = make_float2(p0.y, p1.y);
    const float2 X2 = make_float2(X.x * X.x, X.y * X.y);
    const float2 Y2 = make_float2(Y.x * Y.x, Y.y * Y.y);
    const float2 XY = make_float2(X.x * Y.x, X.y * Y.y);

    float2 den = make_float2(0.f, 0.f);
    float2 R   = make_float2(0.f, 0.f);
    float2 G   = make_float2(0.f, 0.f);
    float2 B   = make_float2(0.f, 0.f);

    #pragma unroll 4
    for (int k = 0; k < KG; ++k) {
        const float4 q0 = params[3 * k + 0];   // ca cb cc cd
        const float4 q1 = params[3 * k + 1];   // ce cf c0 c1
        const float4 q2 = params[3 * k + 2];   // c2 - - -

        float2 e = make_float2(q1.y, q1.y);    // cf
        e = pk_fma_s(q1.x, Y,  e);             // + ce*y
        e = pk_fma_s(q0.w, X,  e);             // + cd*x
        e = pk_fma_s(q0.z, XY, e);             // + cc*xy
        e = pk_fma_s(q0.y, Y2, e);             // + cb*y^2
        e = pk_fma_s(q0.x, X2, e);             // + ca*x^2

        const float2 w = make_float2(__expf(e.x), __expf(e.y));

        den = make_float2(den.x + w.x, den.y + w.y);
        R   = pk_fma_s(q1.z, w, R);
        G   = pk_fma_s(q1.w, w, G);
        B   = pk_fma_s(q2.x, w, B);
    }

    const float inv0 = 1.0f / (den.x + EPSF);
    const float inv1 = 1.0f / (den.y + EPSF);

    out[3 * pix0 + 0] = fminf(fmaxf(R.x * inv0, 0.f), 1.f);
    out[3 * pix0 + 1] = fminf(fmaxf(G.x * inv0, 0.f), 1.f);
    out[3 * pix0 + 2] = fminf(fmaxf(B.x * inv0, 0.f), 1.f);
    out[3 * pix1 + 0] = fminf(fmaxf(R.y * inv1, 0.f), 1.f);
    out[3 * pix1 + 1] = fminf(fmaxf(G.y * inv1, 0.f), 1.f);
    out[3 * pix1 + 2] = fminf(fmaxf(B.y * inv1, 0.f), 1.f);
}

extern "C" void kernel_launch(void* const* d_in, const int* in_sizes, int n_in,
                              void* d_out, int out_size, void* d_ws, size_t ws_size,
                              hipStream_t stream) {
    const float* grid         = (const float*)d_in[0];
    const float* mu           = (const float*)d_in[1];
    const float* log_scales   = (const float*)d_in[2];
    const float* theta        = (const float*)d_in[3];
    const float* color_logits = (const float*)d_in[4];
    const float* log_amp      = (const float*)d_in[5];
    float* out     = (float*)d_out;
    float4* params = (float4*)d_ws;          // 256 * 3 * 16B = 12 KiB

    hipLaunchKernelGGL(gauss_precompute, dim3(1), dim3(KG), 0, stream,
                       mu, log_scales, theta, color_logits, log_amp, params);

    const int threads = 256;
    const int blocks  = (NPIX / 2) / threads;  // 512
    hipLaunchKernelGGL(gauss_render, dim3(blocks), dim3(threads), 0, stream,
                       grid, params, out);
}

// Round 3
// 29.222 us; speedup vs baseline: 1.3796x; 1.2667x over previous
//
#include <hip/hip_runtime.h>
#include <math.h>

#define HH   512
#define WW   512
#define KG   256
#define NPIX (HH * WW)
#define EPSF 1e-6f
#define LOG2E 1.4426950408889634f

// Single fused kernel. Each block folds the K=256 gaussians into a 12-float
// polynomial form in LDS (once, ~50 ops/lane), then each thread renders ONE
// pixel, looping over all gaussians with wave-uniform broadcast LDS reads.
//
//   log2(w_k(x,y)) = ca*x^2 + cb*y^2 + cc*xy + cd*x + ce*y + cf
//
// (log2e folded into all coefficients so the loop uses raw v_exp_f32.)
__global__ __launch_bounds__(256, 4) void gauss_render(
    const float* __restrict__ grid,          // (H,W,2)
    const float* __restrict__ mu,            // (K,2)
    const float* __restrict__ log_scales,    // (K,2)
    const float* __restrict__ theta,         // (K,)
    const float* __restrict__ color_logits,  // (K,3)
    const float* __restrict__ log_amp,       // (K,1)
    float* __restrict__ out)                 // (H,W,3)
{
    __shared__ float4 sp[3 * KG];   // 12 KB

    const int tid = threadIdx.x;
    {
        const int k = tid;                        // blockDim.x == KG == 256
        const float mx  = mu[2 * k + 0];
        const float my  = mu[2 * k + 1];
        const float sx  = expf(log_scales[2 * k + 0]);
        const float sy  = expf(log_scales[2 * k + 1]);
        const float isx = 1.0f / (sx * sx + EPSF);
        const float isy = 1.0f / (sy * sy + EPSF);
        const float t   = theta[k];
        const float c   = cosf(t);
        const float s   = sinf(t);

        // q = A dx^2 + B dy^2 + C dx dy
        const float A = c * c * isx + s * s * isy;
        const float B = s * s * isx + c * c * isy;
        const float C = 2.0f * c * s * (isx - isy);

        const float la  = log_amp[k];
        const float amp = (la > 20.0f) ? la : log1pf(expf(la));  // softplus
        const float lnA = logf(amp);

        // log2 w = (lnA - 0.5 q) * log2e, expanded in x,y
        const float ca = -0.5f * LOG2E * A;
        const float cb = -0.5f * LOG2E * B;
        const float cc = -0.5f * LOG2E * C;
        const float cd = LOG2E * (A * mx + 0.5f * C * my);
        const float ce = LOG2E * (B * my + 0.5f * C * mx);
        const float cf = LOG2E * (lnA - 0.5f * (A * mx * mx + B * my * my + C * mx * my));

        const float c0 = 1.0f / (1.0f + expf(-color_logits[3 * k + 0]));
        const float c1 = 1.0f / (1.0f + expf(-color_logits[3 * k + 1]));
        const float c2 = 1.0f / (1.0f + expf(-color_logits[3 * k + 2]));

        sp[3 * k + 0] = make_float4(ca, cb, cc, cd);
        sp[3 * k + 1] = make_float4(ce, cf, c0, c1);
        sp[3 * k + 2] = make_float4(c2, 0.0f, 0.0f, 0.0f);
    }
    __syncthreads();

    const int pix = blockIdx.x * 256 + tid;       // one pixel per thread

    const float2 p = reinterpret_cast<const float2*>(grid)[pix];
    const float X = p.x, Y = p.y;
    const float X2 = X * X, Y2 = Y * Y, XY = X * Y;

    float den = 0.f, R = 0.f, G = 0.f, B = 0.f;

    #pragma unroll 8
    for (int k = 0; k < KG; ++k) {
        const float4 q0 = sp[3 * k + 0];   // ca cb cc cd
        const float4 q1 = sp[3 * k + 1];   // ce cf c0 c1
        const float4 q2 = sp[3 * k + 2];   // c2 - - -

        float e = fmaf(q1.x, Y, q1.y);     // ce*y + cf
        e = fmaf(q0.w, X,  e);             // + cd*x
        e = fmaf(q0.z, XY, e);             // + cc*xy
        e = fmaf(q0.y, Y2, e);             // + cb*y^2
        e = fmaf(q0.x, X2, e);             // + ca*x^2

        const float w = __builtin_amdgcn_exp2f(e);   // v_exp_f32

        den += w;
        R = fmaf(w, q1.z, R);
        G = fmaf(w, q1.w, G);
        B = fmaf(w, q2.x, B);
    }

    const float inv = 1.0f / (den + EPSF);
    out[3 * pix + 0] = fminf(fmaxf(R * inv, 0.f), 1.f);
    out[3 * pix + 1] = fminf(fmaxf(G * inv, 0.f), 1.f);
    out[3 * pix + 2] = fminf(fmaxf(B * inv, 0.f), 1.f);
}

extern "C" void kernel_launch(void* const* d_in, const int* in_sizes, int n_in,
                              void* d_out, int out_size, void* d_ws, size_t ws_size,
                              hipStream_t stream) {
    const float* grid         = (const float*)d_in[0];
    const float* mu           = (const float*)d_in[1];
    const float* log_scales   = (const float*)d_in[2];
    const float* theta        = (const float*)d_in[3];
    const float* color_logits = (const float*)d_in[4];
    const float* log_amp      = (const float*)d_in[5];
    float* out = (float*)d_out;

    const int threads = 256;
    const int blocks  = NPIX / threads;          // 1024 blocks, 1 px/thread
    hipLaunchKernelGGL(gauss_render, dim3(blocks), dim3(threads), 0, stream,
                       grid, mu, log_scales, theta, color_logits, log_amp, out);
}